// Round 5
// baseline (320.594 us; speedup 1.0000x reference)
//
#include <hip/hip_runtime.h>

typedef __attribute__((ext_vector_type(4))) float floatx4;
typedef __attribute__((ext_vector_type(8))) _Float16 half8;
typedef __attribute__((ext_vector_type(4))) _Float16 half4;

#define TT 2048
#define HIDDEN 2048
#define NH 32
#define NKV 8
#define HD 128
#define QSIZE 4096
#define KVSIZE 1024
#define QKVN 6144
#define QKVNP 6272   // QKVh row stride: +32 gate cols +96 zero
#define WQR 6400     // Wqkvt rows (padded to 256 multiple for 256-tile GEMM)
#define VOFF 5120
#define GOFF 6144
#define WINDOW 512

// ---- unified prep: w_qkv^T, w_o^T (64x64 tiles), cvt, pad-zero, w_g^T --------
__global__ __launch_bounds__(256) void prep_kernel(
    const float* __restrict__ w_qkv, const float* __restrict__ w_o,
    const float* __restrict__ hidden, const float* __restrict__ w_g,
    _Float16* __restrict__ Wqkvt, _Float16* __restrict__ Wot,
    _Float16* __restrict__ Xb) {
  __shared__ float tile[64][68];
  int bid = blockIdx.x;
  int tid = threadIdx.x;
  if (bid >= 5120) {
    if (bid < 7168) {
      int i = ((bid - 5120) * 256 + tid) * 8;
      float4 a = *(const float4*)&hidden[i];
      float4 b = *(const float4*)&hidden[i + 4];
      alignas(16) _Float16 o[8] = {(_Float16)a.x, (_Float16)a.y, (_Float16)a.z, (_Float16)a.w,
                                   (_Float16)b.x, (_Float16)b.y, (_Float16)b.z, (_Float16)b.w};
      *(uint4*)&Xb[i] = *(const uint4*)o;
    } else if (bid < 7392) {
      // zero rows GOFF+NH .. WQR-1 (224 rows)
      int i = ((bid - 7168) * 256 + tid) * 8;
      *(uint4*)&Wqkvt[(size_t)(GOFF + NH) * HIDDEN + i] = (uint4){0, 0, 0, 0};
    } else {
      // w_g [2048][32] -> Wqkvt rows GOFF..GOFF+31 (32x32 tile per block)
      int br = (bid - 7392) * 32;
      int c = tid & 31, r0 = tid >> 5;
      __shared__ float gt[32][33];
#pragma unroll
      for (int i = 0; i < 4; ++i) {
        int r = r0 + 8 * i;
        gt[r][c] = w_g[(size_t)(br + r) * NH + c];
      }
      __syncthreads();
#pragma unroll
      for (int i = 0; i < 4; ++i) {
        int r = r0 + 8 * i;
        Wqkvt[(size_t)(GOFF + r) * HIDDEN + br + c] = (_Float16)gt[c][r];
      }
    }
    return;
  }
  const float* in;
  _Float16* out;
  int R, C, tilesX, t;
  if (bid < 3072) { in = w_qkv; out = Wqkvt; R = HIDDEN; C = QKVN; tilesX = 96; t = bid; }
  else           { in = w_o;   out = Wot;   R = QSIZE;  C = HIDDEN; tilesX = 32; t = bid - 3072; }
  int bc = (t % tilesX) * 64, br = (t / tilesX) * 64;
  int rr = tid >> 4, l16 = tid & 15;
#pragma unroll
  for (int it = 0; it < 4; ++it) {
    int r = rr + it * 16;
    *(float4*)&tile[r][l16 * 4] = *(const float4*)&in[(size_t)(br + r) * C + bc + l16 * 4];
  }
  __syncthreads();
  int orow = tid >> 2, rr0 = (tid & 3) * 16;
  alignas(16) _Float16 tmp[16];
#pragma unroll
  for (int jj = 0; jj < 16; ++jj) tmp[jj] = (_Float16)tile[rr0 + jj][orow];
  *(uint4*)&out[(size_t)(bc + orow) * R + br + rr0] = *(const uint4*)&tmp[0];
  *(uint4*)&out[(size_t)(bc + orow) * R + br + rr0 + 8] = *(const uint4*)&tmp[8];
}

// ---------------- K/V -> fragment-linear repack (z=0: K, z=1: V) -------------
__global__ __launch_bounds__(256) void repack_kv_kernel(const _Float16* __restrict__ Kh,
                                                        const _Float16* __restrict__ QKVh,
                                                        _Float16* __restrict__ Kf,
                                                        _Float16* __restrict__ Vf) {
  __shared__ _Float16 tile[64][136];
  int st = blockIdx.x, kh = blockIdx.y;
  int s0 = st * 64;
  if (blockIdx.z == 0) {
    _Float16* dst = Kf + (size_t)(kh * 32 + st) * 8192;
#pragma unroll
    for (int i = 0; i < 4; ++i) {
      int c = threadIdx.x + i * 256;  // c = jt*256 + kc*64 + quad*16 + n16
      int jt = c >> 8, kc = (c >> 6) & 3, quad = (c >> 4) & 3, n16 = c & 15;
      uint4 v = *(const uint4*)&Kh[((size_t)(s0 + jt * 16 + n16) * NKV + kh) * HD +
                                   kc * 32 + quad * 8];
      *(uint4*)&dst[c * 8] = v;
    }
  } else {
#pragma unroll
    for (int i = 0; i < 4; ++i) {
      int c = threadIdx.x + i * 256;  // c = row*16 + part
      int row = c >> 4, part = c & 15;
      *(uint4*)&tile[row][part * 8] =
          *(const uint4*)&QKVh[(size_t)(s0 + row) * QKVNP + VOFF + kh * HD + part * 8];
    }
    __syncthreads();
    _Float16* dst = Vf + (size_t)(kh * 32 + st) * 8192;
#pragma unroll
    for (int i = 0; i < 4; ++i) {
      int c = threadIdx.x + i * 256;  // c = jd*128 + kc*64 + quad*16 + n16
      int jd = c >> 7, kc = (c >> 6) & 1, quad = (c >> 4) & 3, n16 = c & 15;
      int d = jd * 16 + n16, sb = kc * 32 + quad * 8;
      alignas(16) _Float16 tmp[8];
#pragma unroll
      for (int j = 0; j < 8; ++j) tmp[j] = tile[sb + j][d];
      *(uint4*)&dst[c * 8] = *(const uint4*)tmp;
    }
  }
}

// ---------------- async 16B global->LDS (wave-uniform LDS base + lane*16) -------
__device__ __forceinline__ void async16(const _Float16* g, _Float16* l) {
  __builtin_amdgcn_global_load_lds((const __attribute__((address_space(1))) void*)g,
                                   (__attribute__((address_space(3))) void*)l, 16, 0, 0);
}

// ====== 256x256 8-wave GEMM, BK=32, 4-buffer 3-deep pipeline, vmcnt(8) =======
// A[2048][2048] f16, Bt[WQR=6400][2048] f16, C[2048][QKVNP] f16 (cols masked).
// Per iter t (K-subtile of 32): stage tile t+3 into buf[(t+3)&3] (4 loads/wave),
// 12 ds_read_b128 + 32 MFMA on tile t, vmcnt(8) (tiles t+2,t+3 stay in flight),
// barrier, sched_barrier(0). Issue->wait cover = 3 iters (~1200 cyc >= HBM
// latency); never drains to 0 until the tail. Ledger (induction): entering
// iter t outstanding = {t+1:4, t+2:4}; +stage(t+3)=12; vmcnt(8) completes
// exactly t+1 = next iter's input. Overwrite target buf[(t+3)&3]=buf[(t-1)&3]
// was last read in iter t-1, one barrier ago. Tail: t=61 vmcnt(4), t=62
// vmcnt(0). XCD n-chunk swizzle: xcd=bid&7 owns o=xcd*25+(bid>>3) -> all 8
// m-tiles x ~3 contiguous n-tiles: B chunk (3.2MB) L2-resident per XCD, A
// k-slices shared across XCDs via L3 (kills the 8x B re-stream of (8,25) grid).
#define G256_K 2048

#define STG32(tt)                                                                \
  { int bb_ = ((tt) & 3) * 16384; int ko_ = (tt) * 32;                           \
    async16(As0 + ko_, &lds[bb_ + wave * 1024]);                                 \
    async16(As1 + ko_, &lds[bb_ + wave * 1024 + 512]);                           \
    async16(Bs0 + ko_, &lds[bb_ + 8192 + wave * 1024]);                          \
    async16(Bs1 + ko_, &lds[bb_ + 8192 + wave * 1024 + 512]); }

#define GEMM_BODY(tt)                                                            \
  { const _Float16* LA = &lds[((tt) & 3) * 16384];                               \
    const _Float16* LB = LA + 8192;                                              \
    half8 a[8], b[4];                                                            \
    _Pragma("unroll") for (int i = 0; i < 8; ++i)                                \
      a[i] = *(const half8*)&LA[(wm * 128 + i * 16 + lr) * 32 + swz];            \
    _Pragma("unroll") for (int j = 0; j < 4; ++j)                                \
      b[j] = *(const half8*)&LB[(wn * 64 + j * 16 + lr) * 32 + swz];             \
    __builtin_amdgcn_s_setprio(1);                                               \
    _Pragma("unroll") for (int i = 0; i < 8; ++i)                                \
    _Pragma("unroll") for (int j = 0; j < 4; ++j)                                \
      acc[i][j] = __builtin_amdgcn_mfma_f32_16x16x32_f16(a[i], b[j], acc[i][j], 0, 0, 0); \
    __builtin_amdgcn_s_setprio(0); }

#define VMW(n) asm volatile("s_waitcnt vmcnt(" #n ")" ::: "memory")
#define BAR __builtin_amdgcn_s_barrier()
#define SB0 __builtin_amdgcn_sched_barrier(0)

__global__ __launch_bounds__(512, 2) void gemm256_kernel(
    const _Float16* __restrict__ A, const _Float16* __restrict__ Bt,
    _Float16* __restrict__ C) {
  __shared__ _Float16 lds[65536];  // 128 KiB = 4 bufs x (A 256x32 | B 256x32)
  int tid = threadIdx.x;
  int wave = tid >> 6, lane = tid & 63;
  int wm = wave >> 2, wn = wave & 3;
  int lr = lane & 15, quad = lane >> 4;
  int swz = (quad ^ (lr & 3)) * 8;  // 4-slot XOR swizzle (64-B rows, 16-B slots)

  // XCD n-chunk decode: 200 blocks, xcd = bid&7 gets 25 consecutive tiles
  int bid = blockIdx.x;
  int o = (bid & 7) * 25 + (bid >> 3);
  int m0 = (o & 7) * 256, n0 = (o >> 3) * 256;

  // staging: wave handles chunks 2w,2w+1 (16 rows each) of A and of B.
  // LDS chunk layout linear (lane*16B); global source pre-swizzled so that
  // physical slot s at row r holds logical k-chunk s^(r&3).
  int lrow = lane >> 2;                             // row within 16-row chunk
  int sslot = ((lane & 3) ^ (lrow & 3)) * 8;        // pre-swizzled k offset (f16)
  int crA0 = wave * 32, crA1 = wave * 32 + 16;
  const _Float16* As0 = A + (size_t)(m0 + crA0 + lrow) * G256_K + sslot;
  const _Float16* As1 = A + (size_t)(m0 + crA1 + lrow) * G256_K + sslot;
  const _Float16* Bs0 = Bt + (size_t)(n0 + crA0 + lrow) * G256_K + sslot;
  const _Float16* Bs1 = Bt + (size_t)(n0 + crA1 + lrow) * G256_K + sslot;

  floatx4 acc[8][4];
#pragma unroll
  for (int i = 0; i < 8; ++i)
#pragma unroll
    for (int j = 0; j < 4; ++j) acc[i][j] = (floatx4){0.f, 0.f, 0.f, 0.f};

  // prologue: stage tiles 0,1,2 (12 loads/wave); wait tile0 (vmcnt 8)
  STG32(0);
  STG32(1);
  STG32(2);
  VMW(8);
  BAR;
  SB0;

  // main: 61 iters with stage(t+3) + vmcnt(8)
  for (int t = 0; t < 61; ++t) {
    STG32(t + 3);
    GEMM_BODY(t);
    VMW(8);
    BAR;
    SB0;
  }
  // tail: t = 61, 62, 63
  GEMM_BODY(61);
  VMW(4);
  BAR;
  SB0;
  GEMM_BODY(62);
  VMW(0);
  BAR;
  SB0;
  GEMM_BODY(63);

  // epilogue: masked f16 stores (C stride QKVNP, cols >= QKVNP dropped)
#pragma unroll
  for (int i = 0; i < 8; ++i)
#pragma unroll
    for (int j = 0; j < 4; ++j)
#pragma unroll
      for (int rr = 0; rr < 4; ++rr) {
        int row = m0 + wm * 128 + i * 16 + quad * 4 + rr;
        int col = n0 + wn * 64 + j * 16 + lr;
        if (col < QKVNP)
          C[(size_t)row * QKVNP + col] = (_Float16)acc[i][j][rr];
      }
}

// band swizzle: 8 m-tiles x all-n bands for B-tile temporal sharing.
__device__ __forceinline__ void swizzle_mn(int& m0, int& n0) {
  int ntiles = gridDim.y;
  int pid = blockIdx.x + blockIdx.y * gridDim.x;
  int band = pid / (8 * ntiles);
  int wi = pid - band * (8 * ntiles);
  m0 = (band * 8 + (wi & 7)) * 128;
  n0 = (wi >> 3) * 128;
}

// ---- split-K MFMA GEMM (BK=64, XOR swizzle) -> fp32 PARTIALS (no atomics) ----
__global__ __launch_bounds__(256, 2) void gemm_bt_splitk_kernel(
    const _Float16* __restrict__ A, const _Float16* __restrict__ Bt,
    float* __restrict__ Cp, int M, int N, int K, int Ks) {
  __shared__ _Float16 As[128 * 64];
  __shared__ _Float16 Bs[128 * 64];
  int tid = threadIdx.x;
  int wave = tid >> 6, lane = tid & 63;
  int wm = wave >> 1, wn = wave & 1;
  int m0, n0;
  swizzle_mn(m0, n0);
  int kb = blockIdx.z * Ks;
  float* C = Cp + (size_t)blockIdx.z * M * N;
  int lr = lane & 15;
  int quad = lane >> 4;
  floatx4 acc[4][4];
#pragma unroll
  for (int i = 0; i < 4; ++i)
#pragma unroll
    for (int j = 0; j < 4; ++j) acc[i][j] = (floatx4){0.f, 0.f, 0.f, 0.f};

  for (int k0 = kb; k0 < kb + Ks; k0 += 64) {
    __syncthreads();
#pragma unroll
    for (int it = 0; it < 4; ++it) {
      int c = tid + it * 256;
      int row = c >> 3, j = c & 7;
      int jj = j ^ (row & 7);
      _Float16* la = &As[it * 2048 + wave * 512];
      _Float16* lb = &Bs[it * 2048 + wave * 512];
      async16(&A[(size_t)(m0 + row) * K + k0 + jj * 8], la);
      async16(&Bt[(size_t)(n0 + row) * K + k0 + jj * 8], lb);
    }
    __syncthreads();
#pragma unroll
    for (int kc = 0; kc < 2; ++kc) {
      int ch = kc * 4 + quad;
      half8 a[4], b[4];
#pragma unroll
      for (int i = 0; i < 4; ++i) {
        int r = wm * 64 + i * 16 + lr;
        a[i] = *(const half8*)&As[r * 64 + (ch ^ (r & 7)) * 8];
      }
#pragma unroll
      for (int j = 0; j < 4; ++j) {
        int r = wn * 64 + j * 16 + lr;
        b[j] = *(const half8*)&Bs[r * 64 + (ch ^ (r & 7)) * 8];
      }
#pragma unroll
      for (int i = 0; i < 4; ++i)
#pragma unroll
        for (int j = 0; j < 4; ++j)
          acc[i][j] = __builtin_amdgcn_mfma_f32_16x16x32_f16(a[i], b[j], acc[i][j], 0, 0, 0);
    }
  }
  int rq = quad * 4;
#pragma unroll
  for (int i = 0; i < 4; ++i)
#pragma unroll
    for (int j = 0; j < 4; ++j)
#pragma unroll
      for (int r = 0; r < 4; ++r) {
        int row = m0 + wm * 64 + i * 16 + rq + r;
        int col = n0 + wn * 64 + j * 16 + lr;
        C[(size_t)row * N + col] = acc[i][j][r];
      }
}

// ---- out = P0 + P1 (fp32, float4-vectorized, exactly covers 2048*2048) ------
__global__ __launch_bounds__(256) void reduce2_kernel(const float* __restrict__ P,
                                                      float* __restrict__ out) {
  size_t i = ((size_t)blockIdx.x * 256 + threadIdx.x) * 8;
  const float* Q = P + (size_t)TT * HIDDEN;
  float4 a0 = *(const float4*)&P[i];
  float4 a1 = *(const float4*)&P[i + 4];
  float4 b0 = *(const float4*)&Q[i];
  float4 b1 = *(const float4*)&Q[i + 4];
  a0.x += b0.x; a0.y += b0.y; a0.z += b0.z; a0.w += b0.w;
  a1.x += b1.x; a1.y += b1.y; a1.z += b1.z; a1.w += b1.w;
  *(float4*)&out[i] = a0;
  *(float4*)&out[i + 4] = a1;
}

// ---------------- per-head RMSNorm + RoPE (wave per row) ----------------
__global__ __launch_bounds__(256) void normrope_kernel(
    const _Float16* __restrict__ qkv, const float* __restrict__ qw,
    const float* __restrict__ kw, const int* __restrict__ positions,
    _Float16* __restrict__ qh, _Float16* __restrict__ khb) {
  int wid = blockIdx.x * 4 + (threadIdx.x >> 6);
  int lane = threadIdx.x & 63;
  int t, hh;
  const _Float16* src;
  _Float16* dst;
  const float* w;
  if (wid < TT * NH) {
    t = wid >> 5; hh = wid & 31;
    src = qkv + (size_t)t * QKVNP + hh * HD;
    dst = qh + ((size_t)t * NH + hh) * HD;
    w = qw;
  } else {
    int r = wid - TT * NH;
    t = r >> 3; hh = r & 7;
    src = qkv + (size_t)t * QKVNP + QSIZE + hh * HD;
    dst = khb + ((size_t)t * NKV + hh) * HD;
    w = kw;
  }
  float x1 = (float)src[lane];
  float x2 = (float)src[lane + 64];
  float ss = x1 * x1 + x2 * x2;
#pragma unroll
  for (int off = 1; off < 64; off <<= 1) ss += __shfl_xor(ss, off);
  float rr = rsqrtf(ss * (1.0f / 128.0f) + 1e-6f);
  float n1 = x1 * rr * w[lane];
  float n2 = x2 * rr * w[lane + 64];
  float pos = (float)positions[t];
  float invf = exp2f(-(float)lane * (13.287712379549449f / 64.0f));  // 10000^(-lane/64)
  float ang = pos * invf;
  float sn, cs;
  sincosf(ang, &sn, &cs);
  dst[lane] = (_Float16)(n1 * cs - n2 * sn);
  dst[lane + 64] = (_Float16)(n2 * cs + n1 * sn);
}

// ---- MFMA sliding-window attention: 16 q-rows/block, 4 blocks/CU residency ---
#define PSTR 68
#define M0 8.0f
__global__ __launch_bounds__(256, 2) void attn_kernel(
    const _Float16* __restrict__ Qh, const _Float16* __restrict__ Kf,
    const _Float16* __restrict__ Vf, const _Float16* __restrict__ QKVh,
    _Float16* __restrict__ Og) {
  const float scale = 0.08838834764831845f;  // 128^-0.5
  __shared__ _Float16 Ps[4][16 * PSTR];
  int tid = threadIdx.x;
  int wave = tid >> 6, lane = tid & 63;
  int n16 = lane & 15, quad = lane >> 4;
  int t0 = blockIdx.x * 16;
  int kh = blockIdx.y;
  int h = kh * 4 + wave;
  _Float16* ps = Ps[wave];

  half8 qf[4];
#pragma unroll
  for (int kc = 0; kc < 4; ++kc)
    qf[kc] = *(const half8*)&Qh[((size_t)(t0 + n16) * NH + h) * HD + kc * 32 + quad * 8];

  floatx4 O[8];
  float lp[4];
#pragma unroll
  for (int jd = 0; jd < 8; ++jd) O[jd] = (floatx4){0.f, 0.f, 0.f, 0.f};
#pragma unroll
  for (int r = 0; r < 4; ++r) lp[r] = 0.f;

  int lo = t0 - (WINDOW - 1);
  if (lo < 0) lo = 0;
  int st0 = lo >> 6;
  int st1 = t0 >> 6;

  half8 kfr[4][4];
  {
    const _Float16* kb = Kf + (size_t)(kh * 32 + st0) * 8192;
#pragma unroll
    for (int jt = 0; jt < 4; ++jt)
#pragma unroll
      for (int kc = 0; kc < 4; ++kc)
        kfr[jt][kc] = *(const half8*)&kb[(jt * 4 + kc) * 512 + lane * 8];
  }

  for (int st = st0; st <= st1; ++st) {
    int s0 = st * 64;
    const _Float16* vb = Vf + (size_t)(kh * 32 + st) * 8192;
    floatx4 S[4];
#pragma unroll
    for (int jt = 0; jt < 4; ++jt) S[jt] = (floatx4){0.f, 0.f, 0.f, 0.f};
#pragma unroll
    for (int jt = 0; jt < 4; ++jt)
#pragma unroll
      for (int kc = 0; kc < 4; ++kc)
        S[jt] = __builtin_amdgcn_mfma_f32_16x16x32_f16(qf[kc], kfr[jt][kc], S[jt], 0, 0, 0);
    if (st < st1) {
      const _Float16* kb = Kf + (size_t)(kh * 32 + st + 1) * 8192;
#pragma unroll
      for (int jt = 0; jt < 4; ++jt)
#pragma unroll
        for (int kc = 0; kc < 4; ++kc)
          kfr[jt][kc] = *(const half8*)&kb[(jt * 4 + kc) * 512 + lane * 8];
    }
    bool interior = (t0 >= s0 + 63) && (t0 + 15 - s0 < WINDOW);
    if (interior) {
#pragma unroll
      for (int r = 0; r < 4; ++r) {
        float rs = 0.f;
#pragma unroll
        for (int jt = 0; jt < 4; ++jt) {
          float p = __expf(__builtin_fmaf(S[jt][r], scale, -M0));
          rs += p;
          ps[(quad * 4 + r) * PSTR + jt * 16 + n16] = (_Float16)p;
        }
        lp[r] += rs;
      }
    } else {
#pragma unroll
      for (int r = 0; r < 4; ++r) {
        int tq = t0 + quad * 4 + r;
        float rs = 0.f;
#pragma unroll
        for (int jt = 0; jt < 4; ++jt) {
          int diff = tq - (s0 + jt * 16 + n16);
          bool ok = (diff >= 0) && (diff < WINDOW);
          float p = ok ? __expf(__builtin_fmaf(S[jt][r], scale, -M0)) : 0.f;
          rs += p;
          ps[(quad * 4 + r) * PSTR + jt * 16 + n16] = (_Float16)p;
        }
        lp[r] += rs;
      }
    }
    half8 pf[2];
#pragma unroll
    for (int kc = 0; kc < 2; ++kc) {
      half4 lo4 = *(const half4*)&ps[n16 * PSTR + kc * 32 + quad * 8];
      half4 hi4 = *(const half4*)&ps[n16 * PSTR + kc * 32 + quad * 8 + 4];
      pf[kc] = (half8){lo4[0], lo4[1], lo4[2], lo4[3], hi4[0], hi4[1], hi4[2], hi4[3]};
    }
#pragma unroll
    for (int jd = 0; jd < 8; ++jd) {
#pragma unroll
      for (int kc = 0; kc < 2; ++kc) {
        half8 vfr = *(const half8*)&vb[(jd * 2 + kc) * 512 + lane * 8];
        O[jd] = __builtin_amdgcn_mfma_f32_16x16x32_f16(pf[kc], vfr, O[jd], 0, 0, 0);
      }
    }
  }
#pragma unroll
  for (int r = 0; r < 4; ++r) {
    float l = lp[r];
#pragma unroll
    for (int off = 1; off < 16; off <<= 1) l += __shfl_xor(l, off);
    int t = t0 + quad * 4 + r;
    float gl = (float)QKVh[(size_t)t * QKVNP + GOFF + h];
    float g = (gl > 0.f) ? gl + log1pf(__expf(-gl)) : log1pf(__expf(gl));
    float inv = g / l;
#pragma unroll
    for (int jd = 0; jd < 8; ++jd)
      Og[(size_t)t * QSIZE + h * HD + jd * 16 + n16] = (_Float16)(O[jd][r] * inv);
  }
}

// ---------------- launcher ----------------
extern "C" void kernel_launch(void* const* d_in, const int* in_sizes, int n_in,
                              void* d_out, int out_size, void* d_ws, size_t ws_size,
                              hipStream_t stream) {
  const int* positions = (const int*)d_in[0];
  const float* hidden = (const float*)d_in[1];
  const float* w_qkv = (const float*)d_in[2];
  const float* w_o = (const float*)d_in[3];
  const float* w_g = (const float*)d_in[4];
  const float* q_norm_w = (const float*)d_in[5];
  const float* k_norm_w = (const float*)d_in[6];
  float* out = (float*)d_out;

  char* ws = (char*)d_ws;
  size_t off = 0;
  auto alloc = [&](size_t bytes) {
    void* p = ws + off;
    off += (bytes + 255) & ~(size_t)255;
    return p;
  };
  _Float16* Xb = (_Float16*)alloc((size_t)TT * HIDDEN * 2);
  _Float16* Wqkvt = (_Float16*)alloc((size_t)WQR * HIDDEN * 2);
  _Float16* Wot = (_Float16*)alloc((size_t)HIDDEN * QSIZE * 2);
  _Float16* QKVh = (_Float16*)alloc((size_t)TT * QKVNP * 2);
  _Float16* Qh = (_Float16*)alloc((size_t)TT * NH * HD * 2);
  _Float16* Kh = (_Float16*)alloc((size_t)TT * NKV * HD * 2);
  _Float16* Kf = (_Float16*)alloc((size_t)NKV * 32 * 8192 * 2);
  _Float16* Vf = (_Float16*)alloc((size_t)NKV * 32 * 8192 * 2);
  _Float16* Og = (_Float16*)alloc((size_t)TT * QSIZE * 2);
  // fp32 split-K partials (2 x 16.8 MB = 33.6 MB) alias the Xb+Wqkvt region
  // (8.4 MB + 26.2 MB = 34.6 MB), dead by the time the O-proj runs.
  float* Cp = (float*)ws;

  prep_kernel<<<7456, 256, 0, stream>>>(w_qkv, w_o, hidden, w_g, Wqkvt, Wot, Xb);
  gemm256_kernel<<<200, 512, 0, stream>>>(Xb, Wqkvt, QKVh);
  normrope_kernel<<<(TT * (NH + NKV)) / 4, 256, 0, stream>>>(QKVh, q_norm_w, k_norm_w,
                                                             positions, Qh, Kh);
  repack_kv_kernel<<<dim3(32, NKV, 2), 256, 0, stream>>>(Kh, QKVh, Kf, Vf);
  attn_kernel<<<dim3(TT / 16, NKV), 256, 0, stream>>>(Qh, Kf, Vf, QKVh, Og);
  gemm_bt_splitk_kernel<<<dim3(TT / 128, HIDDEN / 128, 2), 256, 0, stream>>>(
      Og, Wot, Cp, TT, HIDDEN, QSIZE, QSIZE / 2);
  reduce2_kernel<<<(TT * HIDDEN) / (256 * 8), 256, 0, stream>>>(Cp, out);
}

// Round 6
// 314.223 us; speedup vs baseline: 1.0203x; 1.0203x over previous
//
#include <hip/hip_runtime.h>

typedef __attribute__((ext_vector_type(4))) float floatx4;
typedef __attribute__((ext_vector_type(8))) _Float16 half8;
typedef __attribute__((ext_vector_type(4))) _Float16 half4;

#define TT 2048
#define HIDDEN 2048
#define NH 32
#define NKV 8
#define HD 128
#define QSIZE 4096
#define KVSIZE 1024
#define QKVN 6144
#define QKVNP 6272   // QKVh row stride: +32 gate cols +96 zero
#define WQR 6400     // Wqkvt rows (padded to 256 multiple for 256-tile GEMM)
#define VOFF 5120
#define GOFF 6144
#define WINDOW 512

// ---- unified prep: w_qkv^T, w_o^T (64x64 tiles), cvt, pad-zero, w_g^T --------
__global__ __launch_bounds__(256) void prep_kernel(
    const float* __restrict__ w_qkv, const float* __restrict__ w_o,
    const float* __restrict__ hidden, const float* __restrict__ w_g,
    _Float16* __restrict__ Wqkvt, _Float16* __restrict__ Wot,
    _Float16* __restrict__ Xb) {
  __shared__ float tile[64][68];
  int bid = blockIdx.x;
  int tid = threadIdx.x;
  if (bid >= 5120) {
    if (bid < 7168) {
      int i = ((bid - 5120) * 256 + tid) * 8;
      float4 a = *(const float4*)&hidden[i];
      float4 b = *(const float4*)&hidden[i + 4];
      alignas(16) _Float16 o[8] = {(_Float16)a.x, (_Float16)a.y, (_Float16)a.z, (_Float16)a.w,
                                   (_Float16)b.x, (_Float16)b.y, (_Float16)b.z, (_Float16)b.w};
      *(uint4*)&Xb[i] = *(const uint4*)o;
    } else if (bid < 7392) {
      // zero rows GOFF+NH .. WQR-1 (224 rows)
      int i = ((bid - 7168) * 256 + tid) * 8;
      *(uint4*)&Wqkvt[(size_t)(GOFF + NH) * HIDDEN + i] = (uint4){0, 0, 0, 0};
    } else {
      // w_g [2048][32] -> Wqkvt rows GOFF..GOFF+31 (32x32 tile per block)
      int br = (bid - 7392) * 32;
      int c = tid & 31, r0 = tid >> 5;
      __shared__ float gt[32][33];
#pragma unroll
      for (int i = 0; i < 4; ++i) {
        int r = r0 + 8 * i;
        gt[r][c] = w_g[(size_t)(br + r) * NH + c];
      }
      __syncthreads();
#pragma unroll
      for (int i = 0; i < 4; ++i) {
        int r = r0 + 8 * i;
        Wqkvt[(size_t)(GOFF + r) * HIDDEN + br + c] = (_Float16)gt[c][r];
      }
    }
    return;
  }
  const float* in;
  _Float16* out;
  int R, C, tilesX, t;
  if (bid < 3072) { in = w_qkv; out = Wqkvt; R = HIDDEN; C = QKVN; tilesX = 96; t = bid; }
  else           { in = w_o;   out = Wot;   R = QSIZE;  C = HIDDEN; tilesX = 32; t = bid - 3072; }
  int bc = (t % tilesX) * 64, br = (t / tilesX) * 64;
  int rr = tid >> 4, l16 = tid & 15;
#pragma unroll
  for (int it = 0; it < 4; ++it) {
    int r = rr + it * 16;
    *(float4*)&tile[r][l16 * 4] = *(const float4*)&in[(size_t)(br + r) * C + bc + l16 * 4];
  }
  __syncthreads();
  int orow = tid >> 2, rr0 = (tid & 3) * 16;
  alignas(16) _Float16 tmp[16];
#pragma unroll
  for (int jj = 0; jj < 16; ++jj) tmp[jj] = (_Float16)tile[rr0 + jj][orow];
  *(uint4*)&out[(size_t)(bc + orow) * R + br + rr0] = *(const uint4*)&tmp[0];
  *(uint4*)&out[(size_t)(bc + orow) * R + br + rr0 + 8] = *(const uint4*)&tmp[8];
}

// ---------------- K/V -> fragment-linear repack (z=0: K, z=1: V) -------------
__global__ __launch_bounds__(256) void repack_kv_kernel(const _Float16* __restrict__ Kh,
                                                        const _Float16* __restrict__ QKVh,
                                                        _Float16* __restrict__ Kf,
                                                        _Float16* __restrict__ Vf) {
  __shared__ _Float16 tile[64][136];
  int st = blockIdx.x, kh = blockIdx.y;
  int s0 = st * 64;
  if (blockIdx.z == 0) {
    _Float16* dst = Kf + (size_t)(kh * 32 + st) * 8192;
#pragma unroll
    for (int i = 0; i < 4; ++i) {
      int c = threadIdx.x + i * 256;  // c = jt*256 + kc*64 + quad*16 + n16
      int jt = c >> 8, kc = (c >> 6) & 3, quad = (c >> 4) & 3, n16 = c & 15;
      uint4 v = *(const uint4*)&Kh[((size_t)(s0 + jt * 16 + n16) * NKV + kh) * HD +
                                   kc * 32 + quad * 8];
      *(uint4*)&dst[c * 8] = v;
    }
  } else {
#pragma unroll
    for (int i = 0; i < 4; ++i) {
      int c = threadIdx.x + i * 256;  // c = row*16 + part
      int row = c >> 4, part = c & 15;
      *(uint4*)&tile[row][part * 8] =
          *(const uint4*)&QKVh[(size_t)(s0 + row) * QKVNP + VOFF + kh * HD + part * 8];
    }
    __syncthreads();
    _Float16* dst = Vf + (size_t)(kh * 32 + st) * 8192;
#pragma unroll
    for (int i = 0; i < 4; ++i) {
      int c = threadIdx.x + i * 256;  // c = jd*128 + kc*64 + quad*16 + n16
      int jd = c >> 7, kc = (c >> 6) & 1, quad = (c >> 4) & 3, n16 = c & 15;
      int d = jd * 16 + n16, sb = kc * 32 + quad * 8;
      alignas(16) _Float16 tmp[8];
#pragma unroll
      for (int j = 0; j < 8; ++j) tmp[j] = tile[sb + j][d];
      *(uint4*)&dst[c * 8] = *(const uint4*)tmp;
    }
  }
}

// ---------------- async 16B global->LDS (wave-uniform LDS base + lane*16) -------
__device__ __forceinline__ void async16(const _Float16* g, _Float16* l) {
  __builtin_amdgcn_global_load_lds((const __attribute__((address_space(1))) void*)g,
                                   (__attribute__((address_space(3))) void*)l, 16, 0, 0);
}

// ========== 256x256 8-wave GEMM, m201-style 4-phase/K-tile schedule ==========
// A[2048][2048] f16, Bt[WQR=6400][2048] f16, C[2048][QKVNP] f16 (cols masked).
// BK=64 (128-B rows, 8-slot XOR swizzle -- 0 conflicts, proven R1-R4). LDS =
// 2 dbuf x (A 256x64 | B 256x64) = 128 KiB. Half-tiles: A0/A1/B0/B1 = 128 rows
// x 64, 2 global_load_lds each. Per K-tile S, 4 phases (one output quadrant +
// one half-tile stage each):
//   q1: LDA(mh0)+LDB0 | stage A1(S+1)->buf^1 | BAR | lgkm0+SB | 16 MFMA | BAR
//   q2: LDB1          | stage B1(S+1)->buf^1 | ...
//   q3: LDA(mh1)      | stage B0(S+2)->buf   | ...
//   q4: (reuse frags) | stage A0(S+2)->buf   | ... | vmcnt(4) | BAR
// FIFO ledger (per wave, 2 loads/stage, induction-verified): entering tile S
// outstanding = [B0(S+1),A0(S+1)]; +4 stages -> 12 loads; boundary vmcnt(4)
// completes exactly {B0,A0,A1,B1}(S+1) -- everything tile S+1 reads -- and
// leaves [B0(S+2),A0(S+2)] in flight. Never drains to 0 until tail (S=30:
// vmcnt(0)). Region WAR: A-halves last read q3, staged-over q4; B-halves last
// read q2, staged q3; buf^1 regions free since prev tile -- all >=1 barrier
// between read and stage-issue. lgkmcnt(0)+sched_barrier(0) after the
// mid-phase barrier per rule #18 (MFMA must not hoist past inline-asm waits).
// XCD n-chunk decode kept from R5 (FETCH 106->49 MB measured).
#define G256_K 2048

#define STG_A(fb, h, kt)                                                         \
  async16(pA0 + (size_t)(h) * 128 * G256_K + (kt) * 64, &lds[(fb) + (h) * 8192 + wave * 1024]); \
  async16(pA1 + (size_t)(h) * 128 * G256_K + (kt) * 64, &lds[(fb) + (h) * 8192 + wave * 1024 + 512]);
#define STG_B(fb, h, kt)                                                         \
  async16(pB0 + (size_t)(h) * 128 * G256_K + (kt) * 64, &lds[(fb) + 16384 + (h) * 8192 + wave * 1024]); \
  async16(pB1 + (size_t)(h) * 128 * G256_K + (kt) * 64, &lds[(fb) + 16384 + (h) * 8192 + wave * 1024 + 512]);

#define LDA(mh)                                                                  \
  _Pragma("unroll") for (int fm = 0; fm < 4; ++fm)                               \
  _Pragma("unroll") for (int ks = 0; ks < 2; ++ks)                               \
    a[fm][ks] = *(const half8*)&LA[(wm * 128 + (mh) * 64 + fm * 16 + lr) * 64 +  \
                                   (((ks * 4 + quad) ^ l7) * 8)];
#define LDB(DST, nh)                                                             \
  _Pragma("unroll") for (int fn = 0; fn < 2; ++fn)                               \
  _Pragma("unroll") for (int ks = 0; ks < 2; ++ks)                               \
    DST[fn][ks] = *(const half8*)&LB[(wn * 64 + (nh) * 32 + fn * 16 + lr) * 64 + \
                                     (((ks * 4 + quad) ^ l7) * 8)];
#define MFMAQ(BS, mh, nh)                                                        \
  __builtin_amdgcn_s_setprio(1);                                                 \
  _Pragma("unroll") for (int fm = 0; fm < 4; ++fm)                               \
  _Pragma("unroll") for (int fn = 0; fn < 2; ++fn)                               \
  _Pragma("unroll") for (int ks = 0; ks < 2; ++ks)                               \
    acc[(mh) * 4 + fm][(nh) * 2 + fn] = __builtin_amdgcn_mfma_f32_16x16x32_f16(  \
        a[fm][ks], BS[fn][ks], acc[(mh) * 4 + fm][(nh) * 2 + fn], 0, 0, 0);      \
  __builtin_amdgcn_s_setprio(0);
#define VMW(n) asm volatile("s_waitcnt vmcnt(" #n ")" ::: "memory")
#define LGKM0 asm volatile("s_waitcnt lgkmcnt(0)" ::: "memory")
#define BAR __builtin_amdgcn_s_barrier()
#define SB0 __builtin_amdgcn_sched_barrier(0)

__global__ __launch_bounds__(512, 2) void gemm256_kernel(
    const _Float16* __restrict__ A, const _Float16* __restrict__ Bt,
    _Float16* __restrict__ C) {
  __shared__ _Float16 lds[65536];  // 128 KiB: 2 bufs x (A 256x64 | B 256x64)
  int tid = threadIdx.x;
  int wave = tid >> 6, lane = tid & 63;
  int wm = wave >> 2, wn = wave & 3;
  int lr = lane & 15, quad = lane >> 4, l7 = lane & 7, l3 = lane >> 3;

  // XCD n-chunk decode: 200 blocks, xcd = bid&7 owns 25 consecutive mn-tiles
  int bid = blockIdx.x;
  int o = (bid & 7) * 25 + (bid >> 3);
  int m0 = (o & 7) * 256, n0 = (o >> 3) * 256;

  // staging: wave w stages chunks 2w,2w+1 (8 rows each) of a 128-row half.
  // LDS dest linear (HW: uniform base + lane*16B); global source pre-swizzled
  // (k-chunk l7^l3) so phys slot s at row r holds logical chunk s^(r&7).
  int gsw = (l7 ^ l3) * 8;
  const _Float16* pA0 = A + (size_t)(m0 + wave * 16 + l3) * G256_K + gsw;
  const _Float16* pA1 = A + (size_t)(m0 + wave * 16 + 8 + l3) * G256_K + gsw;
  const _Float16* pB0 = Bt + (size_t)(n0 + wave * 16 + l3) * G256_K + gsw;
  const _Float16* pB1 = Bt + (size_t)(n0 + wave * 16 + 8 + l3) * G256_K + gsw;

  floatx4 acc[8][4];
#pragma unroll
  for (int i = 0; i < 8; ++i)
#pragma unroll
    for (int j = 0; j < 4; ++j) acc[i][j] = (floatx4){0.f, 0.f, 0.f, 0.f};

  // prologue: tile0 (4 halves) + [B0(1),A0(1)] in flight; vmcnt(4) completes
  // tile0 exactly, establishing the steady-state invariant.
  STG_B(0, 0, 0);
  STG_A(0, 0, 0);
  STG_A(0, 1, 0);
  STG_B(0, 1, 0);
  STG_B(32768, 0, 1);
  STG_A(32768, 0, 1);
  VMW(4);
  BAR;
  SB0;

  half8 a[4][2], b0[2][2], b1[2][2];

  for (int S = 0; S < 32; ++S) {
    int cb = (S & 1) << 15;  // current buf f16 offset (32768 per buf)
    int nb = cb ^ 32768;
    const _Float16* LA = &lds[cb];
    const _Float16* LB = &lds[cb + 16384];
    bool s1 = (S + 1) < 32, s2 = (S + 2) < 32;

    // ---- q1: quadrant (mh0, nh0) ----
    LDA(0);
    LDB(b0, 0);
    if (s1) { STG_A(nb, 1, S + 1); }
    BAR;
    LGKM0;
    SB0;
    MFMAQ(b0, 0, 0);
    BAR;
    SB0;

    // ---- q2: quadrant (mh0, nh1) ----
    LDB(b1, 1);
    if (s1) { STG_B(nb, 1, S + 1); }
    BAR;
    LGKM0;
    SB0;
    MFMAQ(b1, 0, 1);
    BAR;
    SB0;

    // ---- q3: quadrant (mh1, nh0) ----
    LDA(1);
    if (s2) { STG_B(cb, 0, S + 2); }
    BAR;
    LGKM0;
    SB0;
    MFMAQ(b0, 1, 0);
    BAR;
    SB0;

    // ---- q4: quadrant (mh1, nh1), tile-boundary counted vmcnt ----
    if (s2) { STG_A(cb, 0, S + 2); }
    BAR;
    SB0;
    MFMAQ(b1, 1, 1);
    if (S < 30) VMW(4);
    else if (S == 30) VMW(0);
    BAR;
    SB0;
  }

  // epilogue: masked f16 stores (C stride QKVNP, cols >= QKVNP dropped)
#pragma unroll
  for (int i = 0; i < 8; ++i)
#pragma unroll
    for (int j = 0; j < 4; ++j)
#pragma unroll
      for (int rr = 0; rr < 4; ++rr) {
        int row = m0 + wm * 128 + i * 16 + quad * 4 + rr;
        int col = n0 + wn * 64 + j * 16 + lr;
        if (col < QKVNP)
          C[(size_t)row * QKVNP + col] = (_Float16)acc[i][j][rr];
      }
}

// band swizzle: 8 m-tiles x all-n bands for B-tile temporal sharing.
__device__ __forceinline__ void swizzle_mn(int& m0, int& n0) {
  int ntiles = gridDim.y;
  int pid = blockIdx.x + blockIdx.y * gridDim.x;
  int band = pid / (8 * ntiles);
  int wi = pid - band * (8 * ntiles);
  m0 = (band * 8 + (wi & 7)) * 128;
  n0 = (wi >> 3) * 128;
}

// ---- split-K MFMA GEMM (BK=64, XOR swizzle) -> fp32 PARTIALS (no atomics) ----
__global__ __launch_bounds__(256, 2) void gemm_bt_splitk_kernel(
    const _Float16* __restrict__ A, const _Float16* __restrict__ Bt,
    float* __restrict__ Cp, int M, int N, int K, int Ks) {
  __shared__ _Float16 As[128 * 64];
  __shared__ _Float16 Bs[128 * 64];
  int tid = threadIdx.x;
  int wave = tid >> 6, lane = tid & 63;
  int wm = wave >> 1, wn = wave & 1;
  int m0, n0;
  swizzle_mn(m0, n0);
  int kb = blockIdx.z * Ks;
  float* C = Cp + (size_t)blockIdx.z * M * N;
  int lr = lane & 15;
  int quad = lane >> 4;
  floatx4 acc[4][4];
#pragma unroll
  for (int i = 0; i < 4; ++i)
#pragma unroll
    for (int j = 0; j < 4; ++j) acc[i][j] = (floatx4){0.f, 0.f, 0.f, 0.f};

  for (int k0 = kb; k0 < kb + Ks; k0 += 64) {
    __syncthreads();
#pragma unroll
    for (int it = 0; it < 4; ++it) {
      int c = tid + it * 256;
      int row = c >> 3, j = c & 7;
      int jj = j ^ (row & 7);
      _Float16* la = &As[it * 2048 + wave * 512];
      _Float16* lb = &Bs[it * 2048 + wave * 512];
      async16(&A[(size_t)(m0 + row) * K + k0 + jj * 8], la);
      async16(&Bt[(size_t)(n0 + row) * K + k0 + jj * 8], lb);
    }
    __syncthreads();
#pragma unroll
    for (int kc = 0; kc < 2; ++kc) {
      int ch = kc * 4 + quad;
      half8 a[4], b[4];
#pragma unroll
      for (int i = 0; i < 4; ++i) {
        int r = wm * 64 + i * 16 + lr;
        a[i] = *(const half8*)&As[r * 64 + (ch ^ (r & 7)) * 8];
      }
#pragma unroll
      for (int j = 0; j < 4; ++j) {
        int r = wn * 64 + j * 16 + lr;
        b[j] = *(const half8*)&Bs[r * 64 + (ch ^ (r & 7)) * 8];
      }
#pragma unroll
      for (int i = 0; i < 4; ++i)
#pragma unroll
        for (int j = 0; j < 4; ++j)
          acc[i][j] = __builtin_amdgcn_mfma_f32_16x16x32_f16(a[i], b[j], acc[i][j], 0, 0, 0);
    }
  }
  int rq = quad * 4;
#pragma unroll
  for (int i = 0; i < 4; ++i)
#pragma unroll
    for (int j = 0; j < 4; ++j)
#pragma unroll
      for (int r = 0; r < 4; ++r) {
        int row = m0 + wm * 64 + i * 16 + rq + r;
        int col = n0 + wn * 64 + j * 16 + lr;
        C[(size_t)row * N + col] = acc[i][j][r];
      }
}

// ---- out = P0 + P1 (fp32, float4-vectorized, exactly covers 2048*2048) ------
__global__ __launch_bounds__(256) void reduce2_kernel(const float* __restrict__ P,
                                                      float* __restrict__ out) {
  size_t i = ((size_t)blockIdx.x * 256 + threadIdx.x) * 8;
  const float* Q = P + (size_t)TT * HIDDEN;
  float4 a0 = *(const float4*)&P[i];
  float4 a1 = *(const float4*)&P[i + 4];
  float4 b0 = *(const float4*)&Q[i];
  float4 b1 = *(const float4*)&Q[i + 4];
  a0.x += b0.x; a0.y += b0.y; a0.z += b0.z; a0.w += b0.w;
  a1.x += b1.x; a1.y += b1.y; a1.z += b1.z; a1.w += b1.w;
  *(float4*)&out[i] = a0;
  *(float4*)&out[i + 4] = a1;
}

// ---------------- per-head RMSNorm + RoPE (wave per row) ----------------
__global__ __launch_bounds__(256) void normrope_kernel(
    const _Float16* __restrict__ qkv, const float* __restrict__ qw,
    const float* __restrict__ kw, const int* __restrict__ positions,
    _Float16* __restrict__ qh, _Float16* __restrict__ khb) {
  int wid = blockIdx.x * 4 + (threadIdx.x >> 6);
  int lane = threadIdx.x & 63;
  int t, hh;
  const _Float16* src;
  _Float16* dst;
  const float* w;
  if (wid < TT * NH) {
    t = wid >> 5; hh = wid & 31;
    src = qkv + (size_t)t * QKVNP + hh * HD;
    dst = qh + ((size_t)t * NH + hh) * HD;
    w = qw;
  } else {
    int r = wid - TT * NH;
    t = r >> 3; hh = r & 7;
    src = qkv + (size_t)t * QKVNP + QSIZE + hh * HD;
    dst = khb + ((size_t)t * NKV + hh) * HD;
    w = kw;
  }
  float x1 = (float)src[lane];
  float x2 = (float)src[lane + 64];
  float ss = x1 * x1 + x2 * x2;
#pragma unroll
  for (int off = 1; off < 64; off <<= 1) ss += __shfl_xor(ss, off);
  float rr = rsqrtf(ss * (1.0f / 128.0f) + 1e-6f);
  float n1 = x1 * rr * w[lane];
  float n2 = x2 * rr * w[lane + 64];
  float pos = (float)positions[t];
  float invf = exp2f(-(float)lane * (13.287712379549449f / 64.0f));  // 10000^(-lane/64)
  float ang = pos * invf;
  float sn, cs;
  sincosf(ang, &sn, &cs);
  dst[lane] = (_Float16)(n1 * cs - n2 * sn);
  dst[lane + 64] = (_Float16)(n2 * cs + n1 * sn);
}

// ---- MFMA sliding-window attention: 16 q-rows/block, 4 blocks/CU residency ---
#define PSTR 68
#define M0 8.0f
__global__ __launch_bounds__(256, 2) void attn_kernel(
    const _Float16* __restrict__ Qh, const _Float16* __restrict__ Kf,
    const _Float16* __restrict__ Vf, const _Float16* __restrict__ QKVh,
    _Float16* __restrict__ Og) {
  const float scale = 0.08838834764831845f;  // 128^-0.5
  __shared__ _Float16 Ps[4][16 * PSTR];
  int tid = threadIdx.x;
  int wave = tid >> 6, lane = tid & 63;
  int n16 = lane & 15, quad = lane >> 4;
  int t0 = blockIdx.x * 16;
  int kh = blockIdx.y;
  int h = kh * 4 + wave;
  _Float16* ps = Ps[wave];

  half8 qf[4];
#pragma unroll
  for (int kc = 0; kc < 4; ++kc)
    qf[kc] = *(const half8*)&Qh[((size_t)(t0 + n16) * NH + h) * HD + kc * 32 + quad * 8];

  floatx4 O[8];
  float lp[4];
#pragma unroll
  for (int jd = 0; jd < 8; ++jd) O[jd] = (floatx4){0.f, 0.f, 0.f, 0.f};
#pragma unroll
  for (int r = 0; r < 4; ++r) lp[r] = 0.f;

  int lo = t0 - (WINDOW - 1);
  if (lo < 0) lo = 0;
  int st0 = lo >> 6;
  int st1 = t0 >> 6;

  half8 kfr[4][4];
  {
    const _Float16* kb = Kf + (size_t)(kh * 32 + st0) * 8192;
#pragma unroll
    for (int jt = 0; jt < 4; ++jt)
#pragma unroll
      for (int kc = 0; kc < 4; ++kc)
        kfr[jt][kc] = *(const half8*)&kb[(jt * 4 + kc) * 512 + lane * 8];
  }

  for (int st = st0; st <= st1; ++st) {
    int s0 = st * 64;
    const _Float16* vb = Vf + (size_t)(kh * 32 + st) * 8192;
    floatx4 S[4];
#pragma unroll
    for (int jt = 0; jt < 4; ++jt) S[jt] = (floatx4){0.f, 0.f, 0.f, 0.f};
#pragma unroll
    for (int jt = 0; jt < 4; ++jt)
#pragma unroll
      for (int kc = 0; kc < 4; ++kc)
        S[jt] = __builtin_amdgcn_mfma_f32_16x16x32_f16(qf[kc], kfr[jt][kc], S[jt], 0, 0, 0);
    if (st < st1) {
      const _Float16* kb = Kf + (size_t)(kh * 32 + st + 1) * 8192;
#pragma unroll
      for (int jt = 0; jt < 4; ++jt)
#pragma unroll
        for (int kc = 0; kc < 4; ++kc)
          kfr[jt][kc] = *(const half8*)&kb[(jt * 4 + kc) * 512 + lane * 8];
    }
    bool interior = (t0 >= s0 + 63) && (t0 + 15 - s0 < WINDOW);
    if (interior) {
#pragma unroll
      for (int r = 0; r < 4; ++r) {
        float rs = 0.f;
#pragma unroll
        for (int jt = 0; jt < 4; ++jt) {
          float p = __expf(__builtin_fmaf(S[jt][r], scale, -M0));
          rs += p;
          ps[(quad * 4 + r) * PSTR + jt * 16 + n16] = (_Float16)p;
        }
        lp[r] += rs;
      }
    } else {
#pragma unroll
      for (int r = 0; r < 4; ++r) {
        int tq = t0 + quad * 4 + r;
        float rs = 0.f;
#pragma unroll
        for (int jt = 0; jt < 4; ++jt) {
          int diff = tq - (s0 + jt * 16 + n16);
          bool ok = (diff >= 0) && (diff < WINDOW);
          float p = ok ? __expf(__builtin_fmaf(S[jt][r], scale, -M0)) : 0.f;
          rs += p;
          ps[(quad * 4 + r) * PSTR + jt * 16 + n16] = (_Float16)p;
        }
        lp[r] += rs;
      }
    }
    half8 pf[2];
#pragma unroll
    for (int kc = 0; kc < 2; ++kc) {
      half4 lo4 = *(const half4*)&ps[n16 * PSTR + kc * 32 + quad * 8];
      half4 hi4 = *(const half4*)&ps[n16 * PSTR + kc * 32 + quad * 8 + 4];
      pf[kc] = (half8){lo4[0], lo4[1], lo4[2], lo4[3], hi4[0], hi4[1], hi4[2], hi4[3]};
    }
#pragma unroll
    for (int jd = 0; jd < 8; ++jd) {
#pragma unroll
      for (int kc = 0; kc < 2; ++kc) {
        half8 vfr = *(const half8*)&vb[(jd * 2 + kc) * 512 + lane * 8];
        O[jd] = __builtin_amdgcn_mfma_f32_16x16x32_f16(pf[kc], vfr, O[jd], 0, 0, 0);
      }
    }
  }
#pragma unroll
  for (int r = 0; r < 4; ++r) {
    float l = lp[r];
#pragma unroll
    for (int off = 1; off < 16; off <<= 1) l += __shfl_xor(l, off);
    int t = t0 + quad * 4 + r;
    float gl = (float)QKVh[(size_t)t * QKVNP + GOFF + h];
    float g = (gl > 0.f) ? gl + log1pf(__expf(-gl)) : log1pf(__expf(gl));
    float inv = g / l;
#pragma unroll
    for (int jd = 0; jd < 8; ++jd)
      Og[(size_t)t * QSIZE + h * HD + jd * 16 + n16] = (_Float16)(O[jd][r] * inv);
  }
}

// ---------------- launcher ----------------
extern "C" void kernel_launch(void* const* d_in, const int* in_sizes, int n_in,
                              void* d_out, int out_size, void* d_ws, size_t ws_size,
                              hipStream_t stream) {
  const int* positions = (const int*)d_in[0];
  const float* hidden = (const float*)d_in[1];
  const float* w_qkv = (const float*)d_in[2];
  const float* w_o = (const float*)d_in[3];
  const float* w_g = (const float*)d_in[4];
  const float* q_norm_w = (const float*)d_in[5];
  const float* k_norm_w = (const float*)d_in[6];
  float* out = (float*)d_out;

  char* ws = (char*)d_ws;
  size_t off = 0;
  auto alloc = [&](size_t bytes) {
    void* p = ws + off;
    off += (bytes + 255) & ~(size_t)255;
    return p;
  };
  _Float16* Xb = (_Float16*)alloc((size_t)TT * HIDDEN * 2);
  _Float16* Wqkvt = (_Float16*)alloc((size_t)WQR * HIDDEN * 2);
  _Float16* Wot = (_Float16*)alloc((size_t)HIDDEN * QSIZE * 2);
  _Float16* QKVh = (_Float16*)alloc((size_t)TT * QKVNP * 2);
  _Float16* Qh = (_Float16*)alloc((size_t)TT * NH * HD * 2);
  _Float16* Kh = (_Float16*)alloc((size_t)TT * NKV * HD * 2);
  _Float16* Kf = (_Float16*)alloc((size_t)NKV * 32 * 8192 * 2);
  _Float16* Vf = (_Float16*)alloc((size_t)NKV * 32 * 8192 * 2);
  _Float16* Og = (_Float16*)alloc((size_t)TT * QSIZE * 2);
  // fp32 split-K partials (2 x 16.8 MB = 33.6 MB) alias the Xb+Wqkvt region
  // (8.4 MB + 26.2 MB = 34.6 MB), dead by the time the O-proj runs.
  float* Cp = (float*)ws;

  prep_kernel<<<7456, 256, 0, stream>>>(w_qkv, w_o, hidden, w_g, Wqkvt, Wot, Xb);
  gemm256_kernel<<<200, 512, 0, stream>>>(Xb, Wqkvt, QKVh);
  normrope_kernel<<<(TT * (NH + NKV)) / 4, 256, 0, stream>>>(QKVh, q_norm_w, k_norm_w,
                                                             positions, Qh, Kh);
  repack_kv_kernel<<<dim3(32, NKV, 2), 256, 0, stream>>>(Kh, QKVh, Kf, Vf);
  attn_kernel<<<dim3(TT / 16, NKV), 256, 0, stream>>>(Qh, Kf, Vf, QKVh, Og);
  gemm_bt_splitk_kernel<<<dim3(TT / 128, HIDDEN / 128, 2), 256, 0, stream>>>(
      Og, Wot, Cp, TT, HIDDEN, QSIZE, QSIZE / 2);
  reduce2_kernel<<<(TT * HIDDEN) / (256 * 8), 256, 0, stream>>>(Cp, out);
}